// Round 1
// baseline (226.268 us; speedup 1.0000x reference)
//
#include <hip/hip_runtime.h>

#define ROWS 16384   // B*N = 4*4096
#define DIM 64
#define NCODES 8192
#define KT 256       // codes per k-tile block
#define RPT 2        // rows per thread

// Map float to order-preserving uint, pack with (0xFFFF - idx) so that
// u64 max = (max score, then lowest index) == jnp.argmax first-max semantics.
__device__ __forceinline__ unsigned long long pack_score(float s, int idx) {
  unsigned u = __float_as_uint(s);
  u ^= (unsigned)((int)u >> 31) | 0x80000000u;
  return ((unsigned long long)u << 32) | (unsigned)(0xFFFF - idx);
}

__global__ void vq_enorm(const float* __restrict__ embed, float* __restrict__ enh) {
  int k = blockIdx.x * 256 + threadIdx.x;
  const float4* e4 = (const float4*)(embed + (size_t)k * DIM);
  float a = 0.f, b = 0.f, c = 0.f, d = 0.f;
#pragma unroll
  for (int i = 0; i < DIM / 4; ++i) {
    float4 v = e4[i];
    a = fmaf(v.x, v.x, a);
    b = fmaf(v.y, v.y, b);
    c = fmaf(v.z, v.z, c);
    d = fmaf(v.w, v.w, d);
  }
  enh[k] = 0.5f * ((a + b) + (c + d));  // ||e||^2 / 2
}

// Each thread owns 2 rows (x in registers), scans a 256-code tile.
// embed row address is wave-uniform -> scalar loads through constant cache.
__global__ __launch_bounds__(256, 2) void vq_score(
    const float* __restrict__ x, const float* __restrict__ embed,
    const float* __restrict__ enh, unsigned long long* __restrict__ best) {
  const int tid = threadIdx.x;
  const int row0 = (blockIdx.x * 256 + tid) * RPT;
  const int c0 = blockIdx.y * KT;

  float4 xa[16], xb[16];
  const float4* xg = (const float4*)(x + (size_t)row0 * DIM);
#pragma unroll
  for (int i = 0; i < 16; ++i) { xa[i] = xg[i]; xb[i] = xg[16 + i]; }

  float bsA = -3.4e38f, bsB = -3.4e38f;
  int bcA = 0, bcB = 0;
#pragma unroll 2
  for (int c = c0; c < c0 + KT; ++c) {
    const float4* e4 = (const float4*)(embed + (size_t)c * DIM);
    float a0 = 0.f, a1 = 0.f, a2 = 0.f, a3 = 0.f;
    float b0 = 0.f, b1 = 0.f, b2 = 0.f, b3 = 0.f;
#pragma unroll
    for (int i = 0; i < 16; ++i) {
      float4 ev = e4[i];
      a0 = fmaf(xa[i].x, ev.x, a0);
      a1 = fmaf(xa[i].y, ev.y, a1);
      a2 = fmaf(xa[i].z, ev.z, a2);
      a3 = fmaf(xa[i].w, ev.w, a3);
      b0 = fmaf(xb[i].x, ev.x, b0);
      b1 = fmaf(xb[i].y, ev.y, b1);
      b2 = fmaf(xb[i].z, ev.z, b2);
      b3 = fmaf(xb[i].w, ev.w, b3);
    }
    float eh = enh[c];
    float sA = ((a0 + a1) + (a2 + a3)) - eh;  // x.e - ||e||^2/2 (same argmax as ref dist)
    float sB = ((b0 + b1) + (b2 + b3)) - eh;
    if (sA > bsA) { bsA = sA; bcA = c; }      // strict > keeps first max within tile
    if (sB > bsB) { bsB = sB; bcB = c; }
  }
  atomicMax(&best[row0], pack_score(bsA, bcA));
  atomicMax(&best[row0 + 1], pack_score(bsB, bcB));
}

__global__ void vq_finalize(const unsigned long long* __restrict__ best,
                            const float* __restrict__ embed,
                            const float* __restrict__ node_mask,
                            float* __restrict__ quant,
                            float* __restrict__ out_idx,
                            float* __restrict__ counts) {
  int gid = blockIdx.x * 256 + threadIdx.x;  // ROWS*64 threads
  int row = gid >> 6, d = gid & 63;
  unsigned long long p = best[row];
  int idx = 0xFFFF - (int)(p & 0xFFFFull);
  quant[gid] = embed[(size_t)idx * DIM + d];
  if (d == 0) {
    out_idx[row] = (float)idx;
    atomicAdd(&counts[idx], node_mask[row]);  // exact: addends are 1.0f
  }
}

__global__ void vq_perplexity(const float* __restrict__ counts, float* __restrict__ out) {
  int tid = threadIdx.x;
  float acc = 0.f;
  for (int k = tid; k < NCODES; k += 256) {
    float p = counts[k] * (1.0f / (float)ROWS);
    acc += p * logf(p + 1e-10f);
  }
#pragma unroll
  for (int off = 32; off > 0; off >>= 1) acc += __shfl_down(acc, off);
  __shared__ float red[4];
  if ((tid & 63) == 0) red[tid >> 6] = acc;
  __syncthreads();
  if (tid == 0) out[0] = expf(-((red[0] + red[1]) + (red[2] + red[3])));
}

extern "C" void kernel_launch(void* const* d_in, const int* in_sizes, int n_in,
                              void* d_out, int out_size, void* d_ws, size_t ws_size,
                              hipStream_t stream) {
  const float* x = (const float*)d_in[0];
  const float* node_mask = (const float*)d_in[1];
  const float* embed = (const float*)d_in[2];

  float* out = (float*)d_out;
  float* quant = out;                        // [ROWS*DIM]
  float* out_idx = out + (size_t)ROWS * DIM; // [ROWS] (indices as float)
  float* out_ppl = out_idx + ROWS;           // [1]

  unsigned long long* best = (unsigned long long*)d_ws;       // 131072 B
  float* counts = (float*)((char*)d_ws + ROWS * 8);           // 32768 B
  float* enh = (float*)((char*)d_ws + ROWS * 8 + NCODES * 4); // 32768 B

  // zero best (packed-min) + counts; enh fully overwritten by vq_enorm
  hipMemsetAsync(d_ws, 0, ROWS * 8 + NCODES * 4, stream);
  vq_enorm<<<NCODES / 256, 256, 0, stream>>>(embed, enh);
  vq_score<<<dim3(ROWS / (256 * RPT), NCODES / KT), 256, 0, stream>>>(x, embed, enh, best);
  vq_finalize<<<ROWS * DIM / 256, 256, 0, stream>>>(best, embed, node_mask, quant, out_idx, counts);
  vq_perplexity<<<1, 256, 0, stream>>>(counts, out_ppl);
}